// Round 1
// baseline (371.916 us; speedup 1.0000x reference)
//
#include <hip/hip_runtime.h>
#include <math.h>

namespace {

constexpr int kB = 8;
constexpr int kT = 2048;
constexpr int kC = 1024;
constexpr int kH = 64;
constexpr int TILE = 64;
constexpr int PAD = 68;          // floats per LDS row (64 + 4 pad, keeps 16B align)
constexpr float kScale = 0.125f; // 64^-0.5

// ---------------------------------------------------------------------------
// Kernel 1: q/k/v = x @ {Wq,Wk,Wv}.  Grid: (B*T)/64 = 256 blocks, 256 thr.
// Each block: 64 rows of x; loop C in 64-chunks staged in LDS; each thread
// owns a 4(t) x 4(h) register tile per output matrix.
// ---------------------------------------------------------------------------
__global__ __launch_bounds__(256) void qkv_kernel(
    const float* __restrict__ x,   // [B*T, C]
    const float* __restrict__ Wk,  // [C, H]
    const float* __restrict__ Wq,
    const float* __restrict__ Wv,
    float* __restrict__ qo,        // [B*T, H]
    float* __restrict__ ko,
    float* __restrict__ vo)
{
    __shared__ float xs [TILE][PAD];
    __shared__ float wks[TILE][PAD];
    __shared__ float wqs[TILE][PAD];
    __shared__ float wvs[TILE][PAD];

    const int tid  = threadIdx.x;
    const int tx   = tid & 15;   // h-group: h = tx*4 .. tx*4+3
    const int ty   = tid >> 4;   // t-group: t = ty*4 .. ty*4+3
    const int lrow = ty;         // load decomposition
    const int lcol = tx * 4;
    const long row0 = (long)blockIdx.x * TILE;

    float ak[4][4] = {}, aq[4][4] = {}, av[4][4] = {};

    for (int c0 = 0; c0 < kC; c0 += TILE) {
        #pragma unroll
        for (int r = 0; r < TILE; r += 16) {
            *(float4*)&xs [r + lrow][lcol] = *(const float4*)&x [(row0 + r + lrow) * kC + (c0 + lcol)];
            *(float4*)&wks[r + lrow][lcol] = *(const float4*)&Wk[(long)(c0 + r + lrow) * kH + lcol];
            *(float4*)&wqs[r + lrow][lcol] = *(const float4*)&Wq[(long)(c0 + r + lrow) * kH + lcol];
            *(float4*)&wvs[r + lrow][lcol] = *(const float4*)&Wv[(long)(c0 + r + lrow) * kH + lcol];
        }
        __syncthreads();

        for (int c = 0; c < TILE; c += 4) {
            float4 xv[4];
            #pragma unroll
            for (int i = 0; i < 4; ++i) xv[i] = *(const float4*)&xs[ty * 4 + i][c];
            float4 wk4[4], wq4[4], wv4[4];
            #pragma unroll
            for (int u = 0; u < 4; ++u) {
                wk4[u] = *(const float4*)&wks[c + u][lcol];
                wq4[u] = *(const float4*)&wqs[c + u][lcol];
                wv4[u] = *(const float4*)&wvs[c + u][lcol];
            }
            #pragma unroll
            for (int i = 0; i < 4; ++i) {
                const float* xp = (const float*)&xv[i];
                #pragma unroll
                for (int u = 0; u < 4; ++u) {
                    const float xe = xp[u];
                    const float* kp = (const float*)&wk4[u];
                    const float* qp = (const float*)&wq4[u];
                    const float* vp = (const float*)&wv4[u];
                    #pragma unroll
                    for (int j = 0; j < 4; ++j) {
                        ak[i][j] += xe * kp[j];
                        aq[i][j] += xe * qp[j];
                        av[i][j] += xe * vp[j];
                    }
                }
            }
        }
        __syncthreads();
    }

    #pragma unroll
    for (int i = 0; i < 4; ++i) {
        const long orow = (row0 + ty * 4 + i) * kH + lcol;
        *(float4*)&ko[orow] = make_float4(ak[i][0], ak[i][1], ak[i][2], ak[i][3]);
        *(float4*)&qo[orow] = make_float4(aq[i][0], aq[i][1], aq[i][2], aq[i][3]);
        *(float4*)&vo[orow] = make_float4(av[i][0], av[i][1], av[i][2], av[i][3]);
    }
}

// ---------------------------------------------------------------------------
// Kernel 2: flash attention (causal, online softmax), fp32 vector.
// Grid: B * (T/64) = 256 blocks, 256 threads. Block = (b, 64-row q-tile).
// Scores phase: thread owns 4(t) x 4(s) with s = tx + 16*j (bank-friendly).
// PV phase:     thread owns 4(t) x 4(h) with h = tx*4 + j.
// m/l per row are replicated (consistently) across the 16-lane row-group.
// ---------------------------------------------------------------------------
__global__ __launch_bounds__(256) void attn_kernel(
    const float* __restrict__ qg,
    const float* __restrict__ kg,
    const float* __restrict__ vg,
    float* __restrict__ outg)
{
    __shared__ float qs[TILE][PAD];
    __shared__ float ks[TILE][PAD];
    __shared__ float vs[TILE][PAD];
    __shared__ float ps[TILE][PAD];

    const int tid  = threadIdx.x;
    const int b    = blockIdx.x >> 5;  // 0..7
    const int tt   = blockIdx.x & 31;  // q-tile index
    const int tx   = tid & 15;
    const int ty   = tid >> 4;
    const int lrow = ty;
    const int lcol = tx * 4;
    const long base = (long)b * kT * kH;

    // load q tile (pre-scaled)
    #pragma unroll
    for (int r = 0; r < TILE; r += 16) {
        float4 qv = *(const float4*)&qg[base + (long)(tt * TILE + r + lrow) * kH + lcol];
        qv.x *= kScale; qv.y *= kScale; qv.z *= kScale; qv.w *= kScale;
        *(float4*)&qs[r + lrow][lcol] = qv;
    }

    float o[4][4] = {};
    float mrow[4] = {-INFINITY, -INFINITY, -INFINITY, -INFINITY};
    float lsum[4] = {0.f, 0.f, 0.f, 0.f};

    for (int st = 0; st <= tt; ++st) {
        #pragma unroll
        for (int r = 0; r < TILE; r += 16) {
            *(float4*)&ks[r + lrow][lcol] = *(const float4*)&kg[base + (long)(st * TILE + r + lrow) * kH + lcol];
            *(float4*)&vs[r + lrow][lcol] = *(const float4*)&vg[base + (long)(st * TILE + r + lrow) * kH + lcol];
        }
        __syncthreads();

        // ---- scores S = q . k^T  (rows t = ty*4+i, cols s = tx + 16*j)
        float s[4][4] = {};
        #pragma unroll 2
        for (int h = 0; h < TILE; h += 4) {
            float4 qv[4], kv[4];
            #pragma unroll
            for (int i = 0; i < 4; ++i) qv[i] = *(const float4*)&qs[ty * 4 + i][h];
            #pragma unroll
            for (int j = 0; j < 4; ++j) kv[j] = *(const float4*)&ks[tx + 16 * j][h];
            #pragma unroll
            for (int i = 0; i < 4; ++i)
                #pragma unroll
                for (int j = 0; j < 4; ++j)
                    s[i][j] += qv[i].x * kv[j].x + qv[i].y * kv[j].y +
                               qv[i].z * kv[j].z + qv[i].w * kv[j].w;
        }

        if (st == tt) {  // causal mask, diagonal tile only
            #pragma unroll
            for (int i = 0; i < 4; ++i)
                #pragma unroll
                for (int j = 0; j < 4; ++j)
                    if (tx + 16 * j > ty * 4 + i) s[i][j] = -INFINITY;
        }

        // ---- online softmax update (per row; replicated over 16-lane group)
        #pragma unroll
        for (int i = 0; i < 4; ++i) {
            float mx = fmaxf(fmaxf(s[i][0], s[i][1]), fmaxf(s[i][2], s[i][3]));
            mx = fmaxf(mx, __shfl_xor(mx, 1));
            mx = fmaxf(mx, __shfl_xor(mx, 2));
            mx = fmaxf(mx, __shfl_xor(mx, 4));
            mx = fmaxf(mx, __shfl_xor(mx, 8));
            const float mnew  = fmaxf(mrow[i], mx);
            const float alpha = __expf(mrow[i] - mnew);
            mrow[i] = mnew;
            float psum = 0.f;
            #pragma unroll
            for (int j = 0; j < 4; ++j) {
                s[i][j] = __expf(s[i][j] - mnew);
                psum += s[i][j];
            }
            psum += __shfl_xor(psum, 1);
            psum += __shfl_xor(psum, 2);
            psum += __shfl_xor(psum, 4);
            psum += __shfl_xor(psum, 8);
            lsum[i] = lsum[i] * alpha + psum;
            #pragma unroll
            for (int j = 0; j < 4; ++j) {
                o[i][j] *= alpha;
                ps[ty * 4 + i][tx + 16 * j] = s[i][j];
            }
        }
        __syncthreads();

        // ---- O += P @ V  (rows t = ty*4+i, cols h = tx*4+j)
        #pragma unroll 2
        for (int s0 = 0; s0 < TILE; s0 += 4) {
            float4 pv[4], vv[4];
            #pragma unroll
            for (int i = 0; i < 4; ++i) pv[i] = *(const float4*)&ps[ty * 4 + i][s0];
            #pragma unroll
            for (int u = 0; u < 4; ++u) vv[u] = *(const float4*)&vs[s0 + u][lcol];
            #pragma unroll
            for (int i = 0; i < 4; ++i) {
                const float* pp = (const float*)&pv[i];
                #pragma unroll
                for (int u = 0; u < 4; ++u) {
                    const float pe = pp[u];
                    const float* ve = (const float*)&vv[u];
                    #pragma unroll
                    for (int j = 0; j < 4; ++j) o[i][j] += pe * ve[j];
                }
            }
        }
        __syncthreads();
    }

    // ---- epilogue: normalize and store
    #pragma unroll
    for (int i = 0; i < 4; ++i) {
        const float inv = 1.0f / lsum[i];
        float4 r;
        r.x = o[i][0] * inv; r.y = o[i][1] * inv;
        r.z = o[i][2] * inv; r.w = o[i][3] * inv;
        *(float4*)&outg[base + (long)(tt * TILE + ty * 4 + i) * kH + lcol] = r;
    }
}

} // anonymous namespace

extern "C" void kernel_launch(void* const* d_in, const int* in_sizes, int n_in,
                              void* d_out, int out_size, void* d_ws, size_t ws_size,
                              hipStream_t stream) {
    (void)in_sizes; (void)n_in; (void)out_size; (void)ws_size;
    const float* x  = (const float*)d_in[0];
    const float* Wk = (const float*)d_in[1];
    const float* Wq = (const float*)d_in[2];
    const float* Wv = (const float*)d_in[3];
    float* out = (float*)d_out;

    const size_t nBTH = (size_t)kB * kT * kH;
    float* q = (float*)d_ws;
    float* k = q + nBTH;
    float* v = k + nBTH;

    qkv_kernel<<<(kB * kT) / TILE, 256, 0, stream>>>(x, Wk, Wq, Wv, q, k, v);
    attn_kernel<<<kB * (kT / TILE), 256, 0, stream>>>(q, k, v, out);
}

// Round 2
// 199.731 us; speedup vs baseline: 1.8621x; 1.8621x over previous
//
#include <hip/hip_runtime.h>
#include <math.h>

namespace {

typedef __bf16 bf16_t;
typedef __bf16 bf16x4 __attribute__((ext_vector_type(4)));
typedef __bf16 bf16x8 __attribute__((ext_vector_type(8)));
typedef float  f32x4  __attribute__((ext_vector_type(4)));

constexpr int kB = 8;
constexpr int kT = 2048;
constexpr int kC = 1024;
constexpr int kH = 64;
constexpr int LDK = 72;  // LDS row stride in bf16 (144B -> frag reads are <=2-way conflicts)

// ---------------------------------------------------------------------------
// Preconvert: wsT[3][64][1024] bf16 = {Wk,Wq,Wv}^T, Wq pre-scaled by H^-0.5.
// k-contiguous rows so GEMM B-fragments are single ds_read_b128.
// ---------------------------------------------------------------------------
__global__ __launch_bounds__(256) void wt_kernel(
    const float* __restrict__ Wk, const float* __restrict__ Wq,
    const float* __restrict__ Wv, bf16_t* __restrict__ wsT)
{
    const int g = blockIdx.x * 256 + threadIdx.x;   // 0 .. 3*64*1024-1
    const int wsel = g >> 16;
    const int rem  = g & 65535;
    const int h = rem >> 10, c = rem & 1023;
    const float* W = (wsel == 0) ? Wk : (wsel == 1) ? Wq : Wv;
    float v = W[c * kH + h];
    if (wsel == 1) v *= 0.125f;   // fold attention scale into q (exact pow2)
    wsT[g] = (bf16_t)v;
}

// ---------------------------------------------------------------------------
// QKV projection, bf16 MFMA. 256 blocks x 256 thr; block = 64 rows of x.
// Outputs: k,q bf16 [B*T,H]; v transposed bf16 [B][H][T] (for PV B-operand).
// Wave w owns 3 of the 12 (Wsel, n-tile) pairs across all 4 m-tiles.
// ---------------------------------------------------------------------------
__global__ __launch_bounds__(256) void qkv_kernel(
    const float* __restrict__ x, const bf16_t* __restrict__ wsT,
    bf16_t* __restrict__ ko, bf16_t* __restrict__ qo, bf16_t* __restrict__ vT)
{
    __shared__ bf16_t xs[64][LDK];
    __shared__ bf16_t ws[192][LDK];

    const int tid = threadIdx.x;
    const int w = tid >> 6, lane = tid & 63;
    const int ml = lane & 15, quad = lane >> 4;
    const long row0 = (long)blockIdx.x * 64;

    f32x4 acc[3][4];
    #pragma unroll
    for (int j = 0; j < 3; ++j)
        #pragma unroll
        for (int mt = 0; mt < 4; ++mt)
            #pragma unroll
            for (int r = 0; r < 4; ++r) acc[j][mt][r] = 0.f;

    for (int c0 = 0; c0 < kC; c0 += 64) {
        #pragma unroll
        for (int it = 0; it < 4; ++it) {          // x tile: 64 rows x 64 k, fp32 -> bf16
            const int idx = tid + it * 256;
            const int r = idx >> 4, c4 = idx & 15;
            const float4 f = *(const float4*)&x[(row0 + r) * kC + c0 + c4 * 4];
            bf16x4 bv; bv[0] = (bf16_t)f.x; bv[1] = (bf16_t)f.y;
                       bv[2] = (bf16_t)f.z; bv[3] = (bf16_t)f.w;
            *(bf16x4*)&xs[r][c4 * 4] = bv;
        }
        #pragma unroll
        for (int it = 0; it < 6; ++it) {          // W^T tiles: 192 rows x 64 k, bf16
            const int idx = tid + it * 256;
            const int r = idx >> 3, c8 = idx & 7;
            *(bf16x8*)&ws[r][c8 * 8] = *(const bf16x8*)&wsT[r * kC + c0 + c8 * 8];
        }
        __syncthreads();

        #pragma unroll
        for (int kh = 0; kh < 64; kh += 32) {
            bf16x8 a[4];
            #pragma unroll
            for (int mt = 0; mt < 4; ++mt)
                a[mt] = *(const bf16x8*)&xs[mt * 16 + ml][kh + quad * 8];
            #pragma unroll
            for (int j = 0; j < 3; ++j) {
                const int pi = 3 * w + j;
                const int wsel = pi >> 2, nt = pi & 3;
                const bf16x8 b = *(const bf16x8*)&ws[wsel * 64 + nt * 16 + ml][kh + quad * 8];
                #pragma unroll
                for (int mt = 0; mt < 4; ++mt)
                    acc[j][mt] = __builtin_amdgcn_mfma_f32_16x16x32_bf16(
                        a[mt], b, acc[j][mt], 0, 0, 0);
            }
        }
        __syncthreads();
    }

    // Epilogue. D layout: row = quad*4+reg, col = lane&15.
    const int bb  = (int)(row0 >> 11);
    const int tb0 = (int)(row0 & (kT - 1));
    #pragma unroll
    for (int j = 0; j < 3; ++j) {
        const int pi = 3 * w + j;
        const int wsel = pi >> 2, nt = pi & 3;
        const int h = nt * 16 + ml;
        #pragma unroll
        for (int mt = 0; mt < 4; ++mt) {
            if (wsel == 2) {                       // v -> transposed [b][h][t], 4 consecutive t
                bf16x4 pv;
                #pragma unroll
                for (int r = 0; r < 4; ++r) pv[r] = (bf16_t)acc[j][mt][r];
                *(bf16x4*)&vT[((long)(bb * kH + h)) * kT + tb0 + mt * 16 + quad * 4] = pv;
            } else {
                bf16_t* dst = (wsel == 0) ? ko : qo;
                #pragma unroll
                for (int r = 0; r < 4; ++r)
                    dst[(row0 + mt * 16 + quad * 4 + r) * kH + h] = (bf16_t)acc[j][mt][r];
            }
        }
    }
}

// ---------------------------------------------------------------------------
// Flash attention, bf16 MFMA, causal, online softmax.
// Grid: B * T/64 = 256 blocks, 256 thr. Wave w owns score/output rows
// [16w,16w+16) -> softmax rows never cross waves; P LDS round-trip is
// intra-wave only (no extra barrier needed).
// ---------------------------------------------------------------------------
__global__ __launch_bounds__(256) void attn_kernel(
    const bf16_t* __restrict__ qg, const bf16_t* __restrict__ kg,
    const bf16_t* __restrict__ vT, float* __restrict__ outg)
{
    __shared__ bf16_t qs[64][LDK];
    __shared__ bf16_t ks[64][LDK];
    __shared__ bf16_t vs[64][LDK];   // V^T tile: [h][s]
    __shared__ bf16_t ps[64][LDK];   // P tile:   [t][s]

    const int tid = threadIdx.x;
    const int w = tid >> 6, lane = tid & 63;
    const int ml = lane & 15, quad = lane >> 4;
    const int b = blockIdx.x >> 5, tt = blockIdx.x & 31;
    const long qb = ((long)b * kT + tt * 64) * kH;

    #pragma unroll
    for (int it = 0; it < 2; ++it) {
        const int idx = tid + it * 256;
        const int r = idx >> 3, c8 = idx & 7;
        *(bf16x8*)&qs[r][c8 * 8] = *(const bf16x8*)&qg[qb + r * kH + c8 * 8];
    }

    f32x4 o[4];
    #pragma unroll
    for (int nt = 0; nt < 4; ++nt)
        #pragma unroll
        for (int r = 0; r < 4; ++r) o[nt][r] = 0.f;
    float m[4] = {-INFINITY, -INFINITY, -INFINITY, -INFINITY};
    float l[4] = {0.f, 0.f, 0.f, 0.f};

    for (int st = 0; st <= tt; ++st) {
        const long kb = ((long)b * kT + st * 64) * kH;
        const long vb = (long)b * kH * kT + st * 64;
        #pragma unroll
        for (int it = 0; it < 2; ++it) {
            const int idx = tid + it * 256;
            const int r = idx >> 3, c8 = idx & 7;
            *(bf16x8*)&ks[r][c8 * 8] = *(const bf16x8*)&kg[kb + r * kH + c8 * 8];
            *(bf16x8*)&vs[r][c8 * 8] = *(const bf16x8*)&vT[vb + (long)r * kT + c8 * 8];
        }
        __syncthreads();

        // S = Q K^T : rows 16w+quad*4+r, cols nt*16+ml
        f32x4 s[4];
        #pragma unroll
        for (int nt = 0; nt < 4; ++nt)
            #pragma unroll
            for (int r = 0; r < 4; ++r) s[nt][r] = 0.f;
        #pragma unroll
        for (int kh = 0; kh < 64; kh += 32) {
            const bf16x8 aq = *(const bf16x8*)&qs[w * 16 + ml][kh + quad * 8];
            #pragma unroll
            for (int nt = 0; nt < 4; ++nt) {
                const bf16x8 bk = *(const bf16x8*)&ks[nt * 16 + ml][kh + quad * 8];
                s[nt] = __builtin_amdgcn_mfma_f32_16x16x32_bf16(aq, bk, s[nt], 0, 0, 0);
            }
        }

        if (st == tt) {                            // causal mask: diagonal tile only
            #pragma unroll
            for (int nt = 0; nt < 4; ++nt)
                #pragma unroll
                for (int r = 0; r < 4; ++r)
                    if (nt * 16 + ml > w * 16 + quad * 4 + r) s[nt][r] = -INFINITY;
        }

        // online softmax; rows of a quad are replicated across its 16 lanes
        #pragma unroll
        for (int r = 0; r < 4; ++r) {
            float mx = fmaxf(fmaxf(s[0][r], s[1][r]), fmaxf(s[2][r], s[3][r]));
            mx = fmaxf(mx, __shfl_xor(mx, 1));
            mx = fmaxf(mx, __shfl_xor(mx, 2));
            mx = fmaxf(mx, __shfl_xor(mx, 4));
            mx = fmaxf(mx, __shfl_xor(mx, 8));
            const float mnew  = fmaxf(m[r], mx);
            const float alpha = __expf(m[r] - mnew);
            m[r] = mnew;
            float pr[4], psum = 0.f;
            #pragma unroll
            for (int nt = 0; nt < 4; ++nt) { pr[nt] = __expf(s[nt][r] - mnew); psum += pr[nt]; }
            psum += __shfl_xor(psum, 1);
            psum += __shfl_xor(psum, 2);
            psum += __shfl_xor(psum, 4);
            psum += __shfl_xor(psum, 8);
            l[r] = l[r] * alpha + psum;
            #pragma unroll
            for (int nt = 0; nt < 4; ++nt) {
                o[nt][r] *= alpha;
                ps[w * 16 + quad * 4 + r][nt * 16 + ml] = (bf16_t)pr[nt];
            }
        }
        // no __syncthreads: ps rows [16w,16w+16) are written and read by wave w only

        // O += P V : A = P[t][s] from ps, B^T = V^T[h][s] from vs
        #pragma unroll
        for (int kh = 0; kh < 64; kh += 32) {
            const bf16x8 ap = *(const bf16x8*)&ps[w * 16 + ml][kh + quad * 8];
            #pragma unroll
            for (int nt = 0; nt < 4; ++nt) {
                const bf16x8 bv = *(const bf16x8*)&vs[nt * 16 + ml][kh + quad * 8];
                o[nt] = __builtin_amdgcn_mfma_f32_16x16x32_bf16(ap, bv, o[nt], 0, 0, 0);
            }
        }
        __syncthreads();                           // protect ks/vs for next iteration
    }

    #pragma unroll
    for (int r = 0; r < 4; ++r) {
        const float inv = 1.0f / l[r];
        #pragma unroll
        for (int nt = 0; nt < 4; ++nt)
            outg[qb + (w * 16 + quad * 4 + r) * kH + nt * 16 + ml] = o[nt][r] * inv;
    }
}

} // anonymous namespace

extern "C" void kernel_launch(void* const* d_in, const int* in_sizes, int n_in,
                              void* d_out, int out_size, void* d_ws, size_t ws_size,
                              hipStream_t stream) {
    (void)in_sizes; (void)n_in; (void)out_size; (void)ws_size;
    const float* x  = (const float*)d_in[0];
    const float* Wk = (const float*)d_in[1];
    const float* Wq = (const float*)d_in[2];
    const float* Wv = (const float*)d_in[3];
    float* out = (float*)d_out;

    bf16_t* wsT = (bf16_t*)d_ws;                          // [3*64*1024]
    bf16_t* k   = wsT + (size_t)3 * kH * kC;              // [B*T*H]
    bf16_t* q   = k + (size_t)kB * kT * kH;               // [B*T*H]
    bf16_t* vT  = q + (size_t)kB * kT * kH;               // [B*H*T]

    wt_kernel<<<(3 * kH * kC) / 256, 256, 0, stream>>>(Wk, Wq, Wv, wsT);
    qkv_kernel<<<(kB * kT) / 64, 256, 0, stream>>>(x, wsT, k, q, vT);
    attn_kernel<<<kB * (kT / 64), 256, 0, stream>>>(q, k, vT, out);
}

// Round 3
// 198.702 us; speedup vs baseline: 1.8717x; 1.0052x over previous
//
#include <hip/hip_runtime.h>
#include <math.h>

namespace {

typedef __bf16 bf16_t;
typedef __bf16 bf16x4 __attribute__((ext_vector_type(4)));
typedef __bf16 bf16x8 __attribute__((ext_vector_type(8)));
typedef float  f32x4  __attribute__((ext_vector_type(4)));

constexpr int kB = 8;
constexpr int kT = 2048;
constexpr int kC = 1024;
constexpr int kH = 64;
constexpr int LDK = 72;   // LDS row stride (bf16): 144B = 9 x 16B, b128-aligned, <=2-way banks

__device__ inline bf16x8 pack8(const float4 a, const float4 b) {
    bf16x8 r;
    r[0] = (bf16_t)a.x; r[1] = (bf16_t)a.y; r[2] = (bf16_t)a.z; r[3] = (bf16_t)a.w;
    r[4] = (bf16_t)b.x; r[5] = (bf16_t)b.y; r[6] = (bf16_t)b.z; r[7] = (bf16_t)b.w;
    return r;
}

// ---------------------------------------------------------------------------
// Preconvert: wsT[3][64][1024] bf16 = {Wk,Wq,Wv}^T, Wq pre-scaled by H^-0.5.
// ---------------------------------------------------------------------------
__global__ __launch_bounds__(256) void wt_kernel(
    const float* __restrict__ Wk, const float* __restrict__ Wq,
    const float* __restrict__ Wv, bf16_t* __restrict__ wsT)
{
    const int g = blockIdx.x * 256 + threadIdx.x;
    const int wsel = g >> 16;
    const int rem  = g & 65535;
    const int h = rem >> 10, c = rem & 1023;
    const float* W = (wsel == 0) ? Wk : (wsel == 1) ? Wq : Wv;
    float v = W[c * kH + h];
    if (wsel == 1) v *= 0.125f;
    wsT[g] = (bf16_t)v;
}

// ---------------------------------------------------------------------------
// QKV projection: no LDS, no barriers. 512 blocks x 256 thr; block = 32 rows.
// Wave w computes 2 m-tiles x its 3 (wsel,nt) pairs; A from x (fp32->bf16
// in-reg, next chunk prefetched), B direct from wsT (L1/L2-resident).
// ---------------------------------------------------------------------------
__global__ __launch_bounds__(256) void qkv_kernel(
    const float* __restrict__ x, const bf16_t* __restrict__ wsT,
    bf16_t* __restrict__ ko, bf16_t* __restrict__ qo, bf16_t* __restrict__ vT)
{
    const int tid = threadIdx.x;
    const int w = tid >> 6, lane = tid & 63;
    const int ml = lane & 15, quad = lane >> 4;
    const long row0 = (long)blockIdx.x * 32;

    const float* xr0 = x + (row0 + ml) * kC + quad * 8;
    const float* xr1 = x + (row0 + 16 + ml) * kC + quad * 8;

    int wsel[3], ntv[3];
    const bf16_t* wr[3];
    #pragma unroll
    for (int j = 0; j < 3; ++j) {
        const int pi = 3 * w + j;
        wsel[j] = pi >> 2; ntv[j] = pi & 3;
        wr[j] = wsT + (long)(wsel[j] * 64 + ntv[j] * 16 + ml) * kC + quad * 8;
    }

    float4 xf[8];
    xf[0] = *(const float4*)&xr0[0];  xf[1] = *(const float4*)&xr0[4];
    xf[2] = *(const float4*)&xr0[32]; xf[3] = *(const float4*)&xr0[36];
    xf[4] = *(const float4*)&xr1[0];  xf[5] = *(const float4*)&xr1[4];
    xf[6] = *(const float4*)&xr1[32]; xf[7] = *(const float4*)&xr1[36];

    f32x4 acc[3][2];
    #pragma unroll
    for (int j = 0; j < 3; ++j)
        #pragma unroll
        for (int mt = 0; mt < 2; ++mt)
            #pragma unroll
            for (int r = 0; r < 4; ++r) acc[j][mt][r] = 0.f;

    for (int c0 = 0; c0 < kC; c0 += 64) {
        const int cn = (c0 + 64) & (kC - 1);   // wraps to 0 on last iter (valid, discarded)
        float4 xn[8];
        xn[0] = *(const float4*)&xr0[cn];      xn[1] = *(const float4*)&xr0[cn + 4];
        xn[2] = *(const float4*)&xr0[cn + 32]; xn[3] = *(const float4*)&xr0[cn + 36];
        xn[4] = *(const float4*)&xr1[cn];      xn[5] = *(const float4*)&xr1[cn + 4];
        xn[6] = *(const float4*)&xr1[cn + 32]; xn[7] = *(const float4*)&xr1[cn + 36];

        bf16x8 bfr[3][2];
        #pragma unroll
        for (int j = 0; j < 3; ++j)
            #pragma unroll
            for (int h2 = 0; h2 < 2; ++h2)
                bfr[j][h2] = *(const bf16x8*)&wr[j][c0 + h2 * 32];

        bf16x8 a[2][2];
        a[0][0] = pack8(xf[0], xf[1]); a[0][1] = pack8(xf[2], xf[3]);
        a[1][0] = pack8(xf[4], xf[5]); a[1][1] = pack8(xf[6], xf[7]);

        #pragma unroll
        for (int j = 0; j < 3; ++j)
            #pragma unroll
            for (int mt = 0; mt < 2; ++mt)
                #pragma unroll
                for (int h2 = 0; h2 < 2; ++h2)
                    acc[j][mt] = __builtin_amdgcn_mfma_f32_16x16x32_bf16(
                        a[mt][h2], bfr[j][h2], acc[j][mt], 0, 0, 0);

        #pragma unroll
        for (int i = 0; i < 8; ++i) xf[i] = xn[i];
    }

    const int bb  = (int)(row0 >> 11);
    const int tb0 = (int)(row0 & (kT - 1));
    #pragma unroll
    for (int j = 0; j < 3; ++j) {
        const int h = ntv[j] * 16 + ml;
        #pragma unroll
        for (int mt = 0; mt < 2; ++mt) {
            if (wsel[j] == 2) {   // v -> transposed [b][h][t]
                bf16x4 pv;
                #pragma unroll
                for (int r = 0; r < 4; ++r) pv[r] = (bf16_t)acc[j][mt][r];
                *(bf16x4*)&vT[((long)(bb * kH + h)) * kT + tb0 + mt * 16 + quad * 4] = pv;
            } else {
                bf16_t* dst = (wsel[j] == 0) ? ko : qo;
                #pragma unroll
                for (int r = 0; r < 4; ++r)
                    dst[(row0 + mt * 16 + quad * 4 + r) * kH + h] = (bf16_t)acc[j][mt][r];
            }
        }
    }
}

// ---------------------------------------------------------------------------
// Flash attention: barrier-free. 512 blocks x 128 thr (2 waves); wave owns 16
// q-rows. K/V frags direct from global (L2-resident); K next-tile prefetched;
// V issued before softmax. P round-trips through per-wave LDS rows only.
// Complementary-pair swizzle balances triangular work across co-resident blocks.
// ---------------------------------------------------------------------------
__global__ __launch_bounds__(128) void attn_kernel(
    const bf16_t* __restrict__ qg, const bf16_t* __restrict__ kg,
    const bf16_t* __restrict__ vT, float* __restrict__ outg)
{
    __shared__ bf16_t ps[32][LDK];

    const int tid = threadIdx.x;
    const int w = tid >> 6, lane = tid & 63;
    const int ml = lane & 15, quad = lane >> 4;
    const int idx = blockIdx.x, b = idx >> 6, r6 = idx & 63;
    const int u = r6 >> 1;
    const int qt = (r6 & 1) ? (63 - u) : u;    // pair (u, 63-u): constant work per pair
    const int t0 = qt * 32 + w * 16;

    const long qoff = ((long)b * kT + t0 + ml) * kH + quad * 8;
    const bf16x8 aq0 = *(const bf16x8*)&qg[qoff];
    const bf16x8 aq1 = *(const bf16x8*)&qg[qoff + 32];

    const bf16_t* kp = kg + ((long)b * kT + ml) * kH + quad * 8;
    const bf16_t* vp = vT + ((long)b * kH + ml) * kT + quad * 8;

    const int stmax = (t0 + 15) >> 6;

    bf16x8 kc[4][2];
    #pragma unroll
    for (int nt = 0; nt < 4; ++nt)
        #pragma unroll
        for (int h2 = 0; h2 < 2; ++h2)
            kc[nt][h2] = *(const bf16x8*)&kp[(nt * 16) * kH + h2 * 32];

    f32x4 o[4];
    #pragma unroll
    for (int nt = 0; nt < 4; ++nt)
        #pragma unroll
        for (int r = 0; r < 4; ++r) o[nt][r] = 0.f;
    float m[4] = {-INFINITY, -INFINITY, -INFINITY, -INFINITY};
    float l[4] = {0.f, 0.f, 0.f, 0.f};

    for (int st = 0; st <= stmax; ++st) {
        // V for current tile: issued now, consumed after softmax
        bf16x8 vv[4][2];
        #pragma unroll
        for (int nt = 0; nt < 4; ++nt)
            #pragma unroll
            for (int h2 = 0; h2 < 2; ++h2)
                vv[nt][h2] = *(const bf16x8*)&vp[(long)(nt * 16) * kT + st * 64 + h2 * 32];

        // K prefetch for next tile (redundant reload on last iter — always valid)
        const int stn = (st < stmax) ? st + 1 : st;
        bf16x8 kn[4][2];
        #pragma unroll
        for (int nt = 0; nt < 4; ++nt)
            #pragma unroll
            for (int h2 = 0; h2 < 2; ++h2)
                kn[nt][h2] = *(const bf16x8*)&kp[(stn * 64 + nt * 16) * kH + h2 * 32];

        // S = Q K^T (Q pre-scaled). rows t0+quad*4+r, cols st*64+nt*16+ml
        f32x4 s[4];
        #pragma unroll
        for (int nt = 0; nt < 4; ++nt)
            #pragma unroll
            for (int r = 0; r < 4; ++r) s[nt][r] = 0.f;
        #pragma unroll
        for (int nt = 0; nt < 4; ++nt) {
            s[nt] = __builtin_amdgcn_mfma_f32_16x16x32_bf16(aq0, kc[nt][0], s[nt], 0, 0, 0);
            s[nt] = __builtin_amdgcn_mfma_f32_16x16x32_bf16(aq1, kc[nt][1], s[nt], 0, 0, 0);
        }

        if (st == stmax) {   // causal mask: only the last tile can straddle the diagonal
            #pragma unroll
            for (int nt = 0; nt < 4; ++nt)
                #pragma unroll
                for (int r = 0; r < 4; ++r)
                    if (st * 64 + nt * 16 + ml > t0 + quad * 4 + r) s[nt][r] = -INFINITY;
        }

        // online softmax (rows live in one 16-lane quad-group; xor<=8 stays inside)
        #pragma unroll
        for (int r = 0; r < 4; ++r) {
            float mx = fmaxf(fmaxf(s[0][r], s[1][r]), fmaxf(s[2][r], s[3][r]));
            mx = fmaxf(mx, __shfl_xor(mx, 1));
            mx = fmaxf(mx, __shfl_xor(mx, 2));
            mx = fmaxf(mx, __shfl_xor(mx, 4));
            mx = fmaxf(mx, __shfl_xor(mx, 8));
            const float mnew  = fmaxf(m[r], mx);
            const float alpha = __expf(m[r] - mnew);
            m[r] = mnew;
            float pr[4], psum = 0.f;
            #pragma unroll
            for (int nt = 0; nt < 4; ++nt) { pr[nt] = __expf(s[nt][r] - mnew); psum += pr[nt]; }
            psum += __shfl_xor(psum, 1);
            psum += __shfl_xor(psum, 2);
            psum += __shfl_xor(psum, 4);
            psum += __shfl_xor(psum, 8);
            l[r] = l[r] * alpha + psum;
            #pragma unroll
            for (int nt = 0; nt < 4; ++nt) {
                o[nt][r] *= alpha;
                ps[w * 16 + quad * 4 + r][nt * 16 + ml] = (bf16_t)pr[nt];
            }
        }
        // no barrier: ps rows [16w,16w+16) are private to wave w

        // O += P V
        const bf16x8 ap0 = *(const bf16x8*)&ps[w * 16 + ml][quad * 8];
        const bf16x8 ap1 = *(const bf16x8*)&ps[w * 16 + ml][32 + quad * 8];
        #pragma unroll
        for (int nt = 0; nt < 4; ++nt) {
            o[nt] = __builtin_amdgcn_mfma_f32_16x16x32_bf16(ap0, vv[nt][0], o[nt], 0, 0, 0);
            o[nt] = __builtin_amdgcn_mfma_f32_16x16x32_bf16(ap1, vv[nt][1], o[nt], 0, 0, 0);
        }

        #pragma unroll
        for (int nt = 0; nt < 4; ++nt)
            #pragma unroll
            for (int h2 = 0; h2 < 2; ++h2) kc[nt][h2] = kn[nt][h2];
    }

    #pragma unroll
    for (int r = 0; r < 4; ++r) {
        const float inv = 1.0f / l[r];
        #pragma unroll
        for (int nt = 0; nt < 4; ++nt)
            outg[((long)b * kT + t0 + quad * 4 + r) * kH + nt * 16 + ml] = o[nt][r] * inv;
    }
}

} // anonymous namespace

extern "C" void kernel_launch(void* const* d_in, const int* in_sizes, int n_in,
                              void* d_out, int out_size, void* d_ws, size_t ws_size,
                              hipStream_t stream) {
    (void)in_sizes; (void)n_in; (void)out_size; (void)ws_size;
    const float* x  = (const float*)d_in[0];
    const float* Wk = (const float*)d_in[1];
    const float* Wq = (const float*)d_in[2];
    const float* Wv = (const float*)d_in[3];
    float* out = (float*)d_out;

    bf16_t* wsT = (bf16_t*)d_ws;                   // [3*64*1024]
    bf16_t* k   = wsT + (size_t)3 * kH * kC;       // [B*T*H]
    bf16_t* q   = k + (size_t)kB * kT * kH;        // [B*T*H]
    bf16_t* vT  = q + (size_t)kB * kT * kH;        // [B*H*T]

    wt_kernel<<<(3 * kH * kC) / 256, 256, 0, stream>>>(Wk, Wq, Wv, wsT);
    qkv_kernel<<<(kB * kT) / 32, 256, 0, stream>>>(x, wsT, k, q, vT);
    attn_kernel<<<kB * 64, 128, 0, stream>>>(q, k, vT, out);
}

// Round 4
// 183.269 us; speedup vs baseline: 2.0293x; 1.0842x over previous
//
#include <hip/hip_runtime.h>
#include <math.h>

namespace {

typedef __bf16 bf16_t;
typedef __bf16 bf16x4 __attribute__((ext_vector_type(4)));
typedef __bf16 bf16x8 __attribute__((ext_vector_type(8)));
typedef float  f32x4  __attribute__((ext_vector_type(4)));

constexpr int kB = 8;
constexpr int kT = 2048;
constexpr int kC = 1024;
constexpr int kH = 64;
constexpr int LDK = 72;   // LDS row stride (bf16): 144B, b128-aligned, <=2-way banks
constexpr int kSplit = 4; // s-splits per q-tile in attention pass 1

__device__ inline bf16x8 pack8(const float4 a, const float4 b) {
    bf16x8 r;
    r[0] = (bf16_t)a.x; r[1] = (bf16_t)a.y; r[2] = (bf16_t)a.z; r[3] = (bf16_t)a.w;
    r[4] = (bf16_t)b.x; r[5] = (bf16_t)b.y; r[6] = (bf16_t)b.z; r[7] = (bf16_t)b.w;
    return r;
}

// ---------------------------------------------------------------------------
// Preconvert: wsT[3][64][1024] bf16 = {Wk,Wq,Wv}^T, Wq pre-scaled by H^-0.5.
// ---------------------------------------------------------------------------
__global__ __launch_bounds__(256) void wt_kernel(
    const float* __restrict__ Wk, const float* __restrict__ Wq,
    const float* __restrict__ Wv, bf16_t* __restrict__ wsT)
{
    const int g = blockIdx.x * 256 + threadIdx.x;
    const int wsel = g >> 16;
    const int rem  = g & 65535;
    const int h = rem >> 10, c = rem & 1023;
    const float* W = (wsel == 0) ? Wk : (wsel == 1) ? Wq : Wv;
    float v = W[c * kH + h];
    if (wsel == 1) v *= 0.125f;
    wsT[g] = (bf16_t)v;
}

// ---------------------------------------------------------------------------
// QKV projection. 512 blocks x 256 thr; block = 32 rows of x.
// x: coalesced fp32 loads (16 lanes = 256B of one row) -> reg prefetch one
// iter ahead -> bf16 pack -> double-buffered LDS, ONE barrier per K-iter.
// W-frags: direct from L2-resident wsT, prefetched one iter ahead in regs.
// Wave w: 3 (wsel,nt) pairs x 2 m-tiles. v stored transposed [b][h][t].
// ---------------------------------------------------------------------------
__global__ __launch_bounds__(256) void qkv_kernel(
    const float* __restrict__ x, const bf16_t* __restrict__ wsT,
    bf16_t* __restrict__ ko, bf16_t* __restrict__ qo, bf16_t* __restrict__ vT)
{
    __shared__ bf16_t xs[2][32][LDK];

    const int tid = threadIdx.x;
    const int w = tid >> 6, lane = tid & 63;
    const int ml = lane & 15, quad = lane >> 4;
    const long row0 = (long)blockIdx.x * 32;

    // staging: thread -> (row = tid>>3, cols (tid&7)*8 .. +7)
    const int srow = tid >> 3;
    const int scol = (tid & 7) * 8;
    const float* xrow = x + (row0 + srow) * kC + scol;

    int wsel[3], ntv[3];
    const bf16_t* wr[3];
    #pragma unroll
    for (int j = 0; j < 3; ++j) {
        const int pi = 3 * w + j;
        wsel[j] = pi >> 2; ntv[j] = pi & 3;
        wr[j] = wsT + (long)(wsel[j] * 64 + ntv[j] * 16 + ml) * kC + quad * 8;
    }

    f32x4 acc[3][2];
    #pragma unroll
    for (int j = 0; j < 3; ++j)
        #pragma unroll
        for (int mt = 0; mt < 2; ++mt)
            #pragma unroll
            for (int r = 0; r < 4; ++r) acc[j][mt][r] = 0.f;

    // prologue: chunk0 -> LDS[0]; chunk1 -> regs; W chunk0 -> regs
    float4 xa = *(const float4*)&xrow[0];
    float4 xb = *(const float4*)&xrow[4];
    *(bf16x8*)&xs[0][srow][scol] = pack8(xa, xb);
    xa = *(const float4*)&xrow[64];
    xb = *(const float4*)&xrow[68];
    bf16x8 wf[3][2], wn[3][2];
    #pragma unroll
    for (int j = 0; j < 3; ++j)
        #pragma unroll
        for (int h2 = 0; h2 < 2; ++h2)
            wf[j][h2] = *(const bf16x8*)&wr[j][h2 * 32];
    __syncthreads();

    #pragma unroll 2
    for (int it = 0; it < 16; ++it) {
        const int buf = it & 1;
        if (it < 15) *(bf16x8*)&xs[buf ^ 1][srow][scol] = pack8(xa, xb);  // chunk it+1
        if (it < 14) {                                                    // chunk it+2
            xa = *(const float4*)&xrow[(it + 2) * 64];
            xb = *(const float4*)&xrow[(it + 2) * 64 + 4];
        }
        const int cn = (it < 15) ? (it + 1) * 64 : it * 64;               // W chunk it+1
        #pragma unroll
        for (int j = 0; j < 3; ++j)
            #pragma unroll
            for (int h2 = 0; h2 < 2; ++h2)
                wn[j][h2] = *(const bf16x8*)&wr[j][cn + h2 * 32];

        bf16x8 a[2][2];
        #pragma unroll
        for (int mt = 0; mt < 2; ++mt)
            #pragma unroll
            for (int h2 = 0; h2 < 2; ++h2)
                a[mt][h2] = *(const bf16x8*)&xs[buf][mt * 16 + ml][h2 * 32 + quad * 8];

        #pragma unroll
        for (int j = 0; j < 3; ++j)
            #pragma unroll
            for (int mt = 0; mt < 2; ++mt)
                #pragma unroll
                for (int h2 = 0; h2 < 2; ++h2)
                    acc[j][mt] = __builtin_amdgcn_mfma_f32_16x16x32_bf16(
                        a[mt][h2], wf[j][h2], acc[j][mt], 0, 0, 0);

        #pragma unroll
        for (int j = 0; j < 3; ++j)
            #pragma unroll
            for (int h2 = 0; h2 < 2; ++h2) wf[j][h2] = wn[j][h2];
        __syncthreads();
    }

    const int bb  = (int)(row0 >> 11);
    const int tb0 = (int)(row0 & (kT - 1));
    #pragma unroll
    for (int j = 0; j < 3; ++j) {
        const int h = ntv[j] * 16 + ml;
        #pragma unroll
        for (int mt = 0; mt < 2; ++mt) {
            if (wsel[j] == 2) {   // v -> transposed [b][h][t]
                bf16x4 pv;
                #pragma unroll
                for (int r = 0; r < 4; ++r) pv[r] = (bf16_t)acc[j][mt][r];
                *(bf16x4*)&vT[((long)(bb * kH + h)) * kT + tb0 + mt * 16 + quad * 4] = pv;
            } else {
                bf16_t* dst = (wsel[j] == 0) ? ko : qo;
                #pragma unroll
                for (int r = 0; r < 4; ++r)
                    dst[(row0 + mt * 16 + quad * 4 + r) * kH + h] = (bf16_t)acc[j][mt][r];
            }
        }
    }
}

// ---------------------------------------------------------------------------
// Attention pass 1: split-s flash. Grid = B * 64(qt) * kSplit blocks, 128 thr
// (2 independent waves; wave owns 16 q-rows; no barriers). Split sp handles
// s-tiles {sp, sp+4, ...} <= stmax. Writes unnormalized partial O + (m,l).
// ---------------------------------------------------------------------------
__global__ __launch_bounds__(128) void attn1_kernel(
    const bf16_t* __restrict__ qg, const bf16_t* __restrict__ kg,
    const bf16_t* __restrict__ vT, float* __restrict__ Opart,
    float* __restrict__ mbuf, float* __restrict__ lbuf)
{
    __shared__ bf16_t ps[32][LDK];

    const int tid = threadIdx.x;
    const int w = tid >> 6, lane = tid & 63;
    const int ml = lane & 15, quad = lane >> 4;
    const int bx = blockIdx.x;
    const int sp = bx & 3;
    const int r6 = (bx >> 2) & 63;
    const int b  = bx >> 8;
    const int u  = r6 >> 1;
    const int qt = (r6 & 1) ? (63 - u) : u;   // complementary pairing
    const int t0 = qt * 32 + w * 16;
    const int p  = (b * 64 + qt) * kSplit + sp;
    float* op = Opart + (long)p * 2048;       // [32][64]
    const int stmax = (t0 + 15) >> 6;

    if (sp > stmax) {                          // no tiles: sentinel partials
        #pragma unroll
        for (int r = 0; r < 4; ++r)
            #pragma unroll
            for (int nt = 0; nt < 4; ++nt)
                op[(w * 16 + quad * 4 + r) * 64 + nt * 16 + ml] = 0.f;
        if (ml == 0)
            #pragma unroll
            for (int r = 0; r < 4; ++r) {
                mbuf[p * 32 + w * 16 + quad * 4 + r] = -INFINITY;
                lbuf[p * 32 + w * 16 + quad * 4 + r] = 0.f;
            }
        return;                                // wave-uniform, no barriers in kernel
    }

    const long qoff = ((long)b * kT + t0 + ml) * kH + quad * 8;
    const bf16x8 aq0 = *(const bf16x8*)&qg[qoff];
    const bf16x8 aq1 = *(const bf16x8*)&qg[qoff + 32];

    const bf16_t* kp = kg + ((long)b * kT + ml) * kH + quad * 8;
    const bf16_t* vp = vT + ((long)b * kH + ml) * kT + quad * 8;

    bf16x8 kc[4][2];
    #pragma unroll
    for (int nt = 0; nt < 4; ++nt)
        #pragma unroll
        for (int h2 = 0; h2 < 2; ++h2)
            kc[nt][h2] = *(const bf16x8*)&kp[(sp * 64 + nt * 16) * kH + h2 * 32];

    f32x4 o[4];
    #pragma unroll
    for (int nt = 0; nt < 4; ++nt)
        #pragma unroll
        for (int r = 0; r < 4; ++r) o[nt][r] = 0.f;
    float m[4] = {-INFINITY, -INFINITY, -INFINITY, -INFINITY};
    float l[4] = {0.f, 0.f, 0.f, 0.f};

    for (int st = sp; st <= stmax; st += kSplit) {
        bf16x8 vv[4][2];
        #pragma unroll
        for (int nt = 0; nt < 4; ++nt)
            #pragma unroll
            for (int h2 = 0; h2 < 2; ++h2)
                vv[nt][h2] = *(const bf16x8*)&vp[(long)(nt * 16) * kT + st * 64 + h2 * 32];

        const int stn = (st + kSplit <= stmax) ? st + kSplit : st;
        bf16x8 kn[4][2];
        #pragma unroll
        for (int nt = 0; nt < 4; ++nt)
            #pragma unroll
            for (int h2 = 0; h2 < 2; ++h2)
                kn[nt][h2] = *(const bf16x8*)&kp[(stn * 64 + nt * 16) * kH + h2 * 32];

        f32x4 s[4];
        #pragma unroll
        for (int nt = 0; nt < 4; ++nt)
            #pragma unroll
            for (int r = 0; r < 4; ++r) s[nt][r] = 0.f;
        #pragma unroll
        for (int nt = 0; nt < 4; ++nt) {
            s[nt] = __builtin_amdgcn_mfma_f32_16x16x32_bf16(aq0, kc[nt][0], s[nt], 0, 0, 0);
            s[nt] = __builtin_amdgcn_mfma_f32_16x16x32_bf16(aq1, kc[nt][1], s[nt], 0, 0, 0);
        }

        if (st == stmax) {  // only the wave's own diagonal tile can be masked
            #pragma unroll
            for (int nt = 0; nt < 4; ++nt)
                #pragma unroll
                for (int r = 0; r < 4; ++r)
                    if (st * 64 + nt * 16 + ml > t0 + quad * 4 + r) s[nt][r] = -INFINITY;
        }

        #pragma unroll
        for (int r = 0; r < 4; ++r) {
            float mx = fmaxf(fmaxf(s[0][r], s[1][r]), fmaxf(s[2][r], s[3][r]));
            mx = fmaxf(mx, __shfl_xor(mx, 1));
            mx = fmaxf(mx, __shfl_xor(mx, 2));
            mx = fmaxf(mx, __shfl_xor(mx, 4));
            mx = fmaxf(mx, __shfl_xor(mx, 8));
            const float mnew  = fmaxf(m[r], mx);
            const float alpha = __expf(m[r] - mnew);
            m[r] = mnew;
            float pr[4], psum = 0.f;
            #pragma unroll
            for (int nt = 0; nt < 4; ++nt) { pr[nt] = __expf(s[nt][r] - mnew); psum += pr[nt]; }
            psum += __shfl_xor(psum, 1);
            psum += __shfl_xor(psum, 2);
            psum += __shfl_xor(psum, 4);
            psum += __shfl_xor(psum, 8);
            l[r] = l[r] * alpha + psum;
            #pragma unroll
            for (int nt = 0; nt < 4; ++nt) {
                o[nt][r] *= alpha;
                ps[w * 16 + quad * 4 + r][nt * 16 + ml] = (bf16_t)pr[nt];
            }
        }
        // ps rows [16w,16w+16) are private to wave w: no barrier

        const bf16x8 ap0 = *(const bf16x8*)&ps[w * 16 + ml][quad * 8];
        const bf16x8 ap1 = *(const bf16x8*)&ps[w * 16 + ml][32 + quad * 8];
        #pragma unroll
        for (int nt = 0; nt < 4; ++nt) {
            o[nt] = __builtin_amdgcn_mfma_f32_16x16x32_bf16(ap0, vv[nt][0], o[nt], 0, 0, 0);
            o[nt] = __builtin_amdgcn_mfma_f32_16x16x32_bf16(ap1, vv[nt][1], o[nt], 0, 0, 0);
        }

        #pragma unroll
        for (int nt = 0; nt < 4; ++nt)
            #pragma unroll
            for (int h2 = 0; h2 < 2; ++h2) kc[nt][h2] = kn[nt][h2];
    }

    // write unnormalized partial O and per-row (m, l)
    #pragma unroll
    for (int r = 0; r < 4; ++r)
        #pragma unroll
        for (int nt = 0; nt < 4; ++nt)
            op[(w * 16 + quad * 4 + r) * 64 + nt * 16 + ml] = o[nt][r];
    if (ml == 0)
        #pragma unroll
        for (int r = 0; r < 4; ++r) {
            mbuf[p * 32 + w * 16 + quad * 4 + r] = m[r];
            lbuf[p * 32 + w * 16 + quad * 4 + r] = l[r];
        }
}

// ---------------------------------------------------------------------------
// Attention pass 2: combine kSplit partials per row. 1024 blocks x 256 thr;
// thread = one float4 of h for one output row.
// ---------------------------------------------------------------------------
__global__ __launch_bounds__(256) void attn2_kernel(
    const float* __restrict__ Opart, const float* __restrict__ mbuf,
    const float* __restrict__ lbuf, float* __restrict__ outg)
{
    const int g = blockIdx.x * 256 + threadIdx.x;   // 0 .. 262143
    const int h4  = (g & 15) * 4;
    const int row = (g >> 4) & 31;
    const int qt  = (g >> 9) & 63;
    const int b   = g >> 15;
    const int p0  = (b * 64 + qt) * kSplit;

    float mm[kSplit];
    float M = -INFINITY;
    #pragma unroll
    for (int sp = 0; sp < kSplit; ++sp) {
        mm[sp] = mbuf[(p0 + sp) * 32 + row];
        M = fmaxf(M, mm[sp]);
    }
    float4 acc = make_float4(0.f, 0.f, 0.f, 0.f);
    float lt = 0.f;
    #pragma unroll
    for (int sp = 0; sp < kSplit; ++sp) {
        const float wgt = __expf(mm[sp] - M);
        lt += wgt * lbuf[(p0 + sp) * 32 + row];
        const float4 ov = *(const float4*)&Opart[(long)(p0 + sp) * 2048 + row * 64 + h4];
        acc.x += wgt * ov.x; acc.y += wgt * ov.y;
        acc.z += wgt * ov.z; acc.w += wgt * ov.w;
    }
    const float inv = 1.0f / lt;
    acc.x *= inv; acc.y *= inv; acc.z *= inv; acc.w *= inv;
    *(float4*)&outg[((long)(b * 64 + qt) * 32 + row) * 64 + h4] = acc;
}

} // anonymous namespace

extern "C" void kernel_launch(void* const* d_in, const int* in_sizes, int n_in,
                              void* d_out, int out_size, void* d_ws, size_t ws_size,
                              hipStream_t stream) {
    (void)in_sizes; (void)n_in; (void)out_size; (void)ws_size;
    const float* x  = (const float*)d_in[0];
    const float* Wk = (const float*)d_in[1];
    const float* Wq = (const float*)d_in[2];
    const float* Wv = (const float*)d_in[3];
    float* out = (float*)d_out;

    const size_t N = (size_t)kB * kT * kH;           // 1M elements
    bf16_t* wsT = (bf16_t*)d_ws;                     // 3*64*1024 bf16
    bf16_t* k   = wsT + (size_t)3 * kH * kC;
    bf16_t* q   = k + N;
    bf16_t* vT  = q + N;
    float* Opart = (float*)(vT + N);                 // [8*64*kSplit][32][64] fp32
    float* mbuf  = Opart + (size_t)kB * 64 * kSplit * 2048;
    float* lbuf  = mbuf + (size_t)kB * 64 * kSplit * 32;

    wt_kernel<<<(3 * kH * kC) / 256, 256, 0, stream>>>(Wk, Wq, Wv, wsT);
    qkv_kernel<<<(kB * kT) / 32, 256, 0, stream>>>(x, wsT, k, q, vT);
    attn1_kernel<<<kB * 64 * kSplit, 128, 0, stream>>>(q, k, vT, Opart, mbuf, lbuf);
    attn2_kernel<<<(kB * kT * kH / 4) / 256, 256, 0, stream>>>(Opart, mbuf, lbuf, out);
}